// Round 1
// baseline (258.500 us; speedup 1.0000x reference)
//
#include <hip/hip_runtime.h>

#define HF 240      // fine height/width
#define HC 60       // coarse height/width
#define STRIDEF 4   // HF/HC
#define PADW 2      // WINDOW//2
#define WIN 5
#define CC 256      // C_COARSE
#define CF 128      // C_FINE
#define NPOS 25     // WIN*WIN
#define LDP 132     // padded LDS stride for patch rows

// ---------------------------------------------------------------------------
// K1: build WT = Wm1^T [128k][128j], W_effT = (Wm2 @ W_dp)^T [256k][128j],
//     b_eff = Wm2 @ b_dp + b_merge  [128]
// grid = 256 blocks (k), block = 128 threads (j)
// ---------------------------------------------------------------------------
__global__ void k_prep(const float* __restrict__ W_dp, const float* __restrict__ b_dp,
                       const float* __restrict__ W_merge, const float* __restrict__ b_merge,
                       float* __restrict__ WT, float* __restrict__ W_effT,
                       float* __restrict__ b_eff) {
    const int k = blockIdx.x;    // 0..255 (coarse dim)
    const int j = threadIdx.x;   // 0..127 (output channel)

    // W_eff[j][k] = sum_q Wm2[j][q] * W_dp[q][k]
    float acc = 0.f;
    for (int q = 0; q < CF; ++q)
        acc += W_merge[j * (2 * CF) + CF + q] * W_dp[q * CC + k];
    W_effT[k * CF + j] = acc;

    if (k < CF) {
        // WT[k][j] = Wm1[j][k]
        WT[k * CF + j] = W_merge[j * (2 * CF) + k];
    }
    if (blockIdx.x == 0) {
        float b = 0.f;
        for (int q = 0; q < CF; ++q)
            b += W_merge[j * (2 * CF) + CF + q] * b_dp[q];
        b_eff[j] = b + b_merge[j];
    }
}

// ---------------------------------------------------------------------------
// K2: c_all[m][j] = b_eff[j] + sum_k W_eff[j][k] * coarse_vec(m)[k]
// 8 matches per block so W_effT is streamed once per 8 matches.
// grid = ceil(2M/8), block = 128
// ---------------------------------------------------------------------------
__global__ void k_coarse(const float* __restrict__ c1, const float* __restrict__ c2,
                         const int* __restrict__ bidx, const int* __restrict__ ridx,
                         const int* __restrict__ cidx, int M,
                         const float* __restrict__ W_effT, const float* __restrict__ b_eff,
                         float* __restrict__ c_all) {
    const int m0 = blockIdx.x * 8;
    const int j  = threadIdx.x;  // 0..127
    const int twoM = 2 * M;
    __shared__ float v[8 * CC];

    const int nm = (twoM - m0) < 8 ? (twoM - m0) : 8;
    // load nm coarse vectors into LDS
    for (int mm = 0; mm < nm; ++mm) {
        int m = m0 + mm;
        const float* src;
        if (m < M) src = c1 + ((size_t)bidx[m] * (HC * HC) + ridx[m]) * CC;
        else       src = c2 + ((size_t)bidx[m - M] * (HC * HC) + cidx[m - M]) * CC;
        v[mm * CC + j]      = src[j];
        v[mm * CC + j + CF] = src[j + CF];
    }
    __syncthreads();

    float acc[8];
    float be = b_eff[j];
    #pragma unroll
    for (int mm = 0; mm < 8; ++mm) acc[mm] = be;

    for (int k = 0; k < CC; ++k) {
        float wv = W_effT[k * CF + j];
        #pragma unroll
        for (int mm = 0; mm < 8; ++mm)
            acc[mm] += wv * v[mm * CC + k];
    }
    for (int mm = 0; mm < nm; ++mm)
        c_all[(size_t)(m0 + mm) * CF + j] = acc[mm];
}

// ---------------------------------------------------------------------------
// K3: main. One block per match. Gather 25x128 patch -> LDS, then
// out[m][p][j] = sum_k patch[p][k] * Wm1[j][k] + c_all[m][j]
// grid = 2M, block = 256
// ---------------------------------------------------------------------------
__global__ __launch_bounds__(256) void k_main(
    const float* __restrict__ f1, const float* __restrict__ f2,
    const int* __restrict__ bidx, const int* __restrict__ ridx,
    const int* __restrict__ cidx, int M,
    const float* __restrict__ WT, const float* __restrict__ c_all,
    float* __restrict__ out) {

    const int m = blockIdx.x;
    const int t = threadIdx.x;

    __shared__ float patch[NPOS * LDP];
    __shared__ float cvec[CF];

    const float* img;
    int b, lin;
    if (m < M) { img = f1; b = bidx[m]; lin = ridx[m]; }
    else       { img = f2; b = bidx[m - M]; lin = cidx[m - M]; }
    const int r = lin / HC, c = lin % HC;
    const int y0 = r * STRIDEF - PADW;
    const int x0 = c * STRIDEF - PADW;

    if (t < CF) cvec[t] = c_all[(size_t)m * CF + t];

    // gather: task = ch*5 + wy ; each task reads 5 contiguous floats (one window row)
    for (int task = t; task < CF * WIN; task += 256) {
        const int ch = task / WIN;
        const int wy = task % WIN;
        const int y = y0 + wy;
        const float* rowp = img + (((size_t)b * CF + ch) * HF + (size_t)(y < 0 ? 0 : y)) * HF;
        const bool yok = (y >= 0) && (y < HF);
        #pragma unroll
        for (int wx = 0; wx < WIN; ++wx) {
            const int x = x0 + wx;
            float val = 0.f;
            if (yok && x >= 0 && x < HF) val = rowp[x];
            patch[(wy * WIN + wx) * LDP + ch] = val;
        }
    }
    __syncthreads();

    const int jg   = t & 31;   // output float4 group: j = 4*jg .. 4*jg+3
    const int pset = t >> 5;   // 0..7 position slot

    float4 a0 = make_float4(0.f, 0.f, 0.f, 0.f);
    float4 a1 = a0, a2 = a0, a3 = a0;

    const float* p0 = patch + (size_t)pset * LDP;
    const float* p1 = patch + (size_t)(pset + 8) * LDP;
    const float* p2 = patch + (size_t)(pset + 16) * LDP;
    const float* p3 = patch + (size_t)24 * LDP;   // only pset==0 accumulates
    const float4* w = (const float4*)WT + jg;
    const bool has4 = (pset == 0);

    #pragma unroll 4
    for (int k = 0; k < CF; ++k) {
        const float4 wv = w[(size_t)k * 32];
        const float s0 = p0[k];
        const float s1 = p1[k];
        const float s2 = p2[k];
        a0.x += s0 * wv.x; a0.y += s0 * wv.y; a0.z += s0 * wv.z; a0.w += s0 * wv.w;
        a1.x += s1 * wv.x; a1.y += s1 * wv.y; a1.z += s1 * wv.z; a1.w += s1 * wv.w;
        a2.x += s2 * wv.x; a2.y += s2 * wv.y; a2.z += s2 * wv.z; a2.w += s2 * wv.w;
        if (has4) {
            const float s3 = p3[k];
            a3.x += s3 * wv.x; a3.y += s3 * wv.y; a3.z += s3 * wv.z; a3.w += s3 * wv.w;
        }
    }

    const float4 cv = *(const float4*)(cvec + jg * 4);
    float* ob = out + (size_t)m * (NPOS * CF) + jg * 4;

    float4 o;
    o.x = a0.x + cv.x; o.y = a0.y + cv.y; o.z = a0.z + cv.z; o.w = a0.w + cv.w;
    *(float4*)(ob + (size_t)pset * CF) = o;
    o.x = a1.x + cv.x; o.y = a1.y + cv.y; o.z = a1.z + cv.z; o.w = a1.w + cv.w;
    *(float4*)(ob + (size_t)(pset + 8) * CF) = o;
    o.x = a2.x + cv.x; o.y = a2.y + cv.y; o.z = a2.z + cv.z; o.w = a2.w + cv.w;
    *(float4*)(ob + (size_t)(pset + 16) * CF) = o;
    if (has4) {
        o.x = a3.x + cv.x; o.y = a3.y + cv.y; o.z = a3.z + cv.z; o.w = a3.w + cv.w;
        *(float4*)(ob + (size_t)24 * CF) = o;
    }
}

// ---------------------------------------------------------------------------
extern "C" void kernel_launch(void* const* d_in, const int* in_sizes, int n_in,
                              void* d_out, int out_size, void* d_ws, size_t ws_size,
                              hipStream_t stream) {
    const float* c1      = (const float*)d_in[0];
    const float* c2      = (const float*)d_in[1];
    const float* f1      = (const float*)d_in[2];
    const float* f2      = (const float*)d_in[3];
    const int*   bidx    = (const int*)d_in[4];
    const int*   ridx    = (const int*)d_in[5];
    const int*   cidx    = (const int*)d_in[6];
    const float* W_dp    = (const float*)d_in[9];
    const float* b_dp    = (const float*)d_in[10];
    const float* W_merge = (const float*)d_in[11];
    const float* b_merge = (const float*)d_in[12];
    const int M = in_sizes[4];

    char* ws = (char*)d_ws;
    float* WT     = (float*)(ws);                 //  64 KB
    float* W_effT = (float*)(ws + (64 << 10));    // 128 KB
    float* b_eff  = (float*)(ws + (192 << 10));   // 512 B
    float* c_all  = (float*)(ws + (256 << 10));   // 2M*128*4 = ~3.07 MB

    hipLaunchKernelGGL(k_prep, dim3(CC), dim3(CF), 0, stream,
                       W_dp, b_dp, W_merge, b_merge, WT, W_effT, b_eff);
    hipLaunchKernelGGL(k_coarse, dim3((2 * M + 7) / 8), dim3(CF), 0, stream,
                       c1, c2, bidx, ridx, cidx, M, W_effT, b_eff, c_all);
    hipLaunchKernelGGL(k_main, dim3(2 * M), dim3(256), 0, stream,
                       f1, f2, bidx, ridx, cidx, M, WT, c_all, (float*)d_out);
}

// Round 2
// 191.260 us; speedup vs baseline: 1.3516x; 1.3516x over previous
//
#include <hip/hip_runtime.h>

#define HF 240      // fine height/width
#define HC 60       // coarse height/width
#define STRIDEF 4   // HF/HC
#define PADW 2      // WINDOW//2
#define WIN 5
#define CC 256      // C_COARSE
#define CF 128      // C_FINE
#define NPOS 25     // WIN*WIN

typedef __bf16 bf16x8 __attribute__((ext_vector_type(8)));
typedef float  f32x4  __attribute__((ext_vector_type(4)));

// ---------------------------------------------------------------------------
// K1: build Wm1h (bf16, row-major [j][k] = W_merge[j][k]),
//     W_effT = (Wm2 @ W_dp)^T [256k][128j] (fp32),
//     b_eff = Wm2 @ b_dp + b_merge [128]
// grid = 256 blocks (k), block = 128 threads (j)
// ---------------------------------------------------------------------------
__global__ void k_prep(const float* __restrict__ W_dp, const float* __restrict__ b_dp,
                       const float* __restrict__ W_merge, const float* __restrict__ b_merge,
                       __bf16* __restrict__ Wm1h, float* __restrict__ W_effT,
                       float* __restrict__ b_eff) {
    const int k = blockIdx.x;    // 0..255 (coarse dim)
    const int j = threadIdx.x;   // 0..127 (output channel)

    // W_eff[j][k] = sum_q Wm2[j][q] * W_dp[q][k]
    float acc = 0.f;
    for (int q = 0; q < CF; ++q)
        acc += W_merge[j * (2 * CF) + CF + q] * W_dp[q * CC + k];
    W_effT[k * CF + j] = acc;

    if (k < CF) {
        // Wm1h[j][k] = bf16(W_merge[j][k])   (first half of W_merge)
        Wm1h[j * CF + k] = (__bf16)W_merge[j * (2 * CF) + k];
    }
    if (blockIdx.x == 0) {
        float b = 0.f;
        for (int q = 0; q < CF; ++q)
            b += W_merge[j * (2 * CF) + CF + q] * b_dp[q];
        b_eff[j] = b + b_merge[j];
    }
}

// ---------------------------------------------------------------------------
// K2: c_all[m][j] = b_eff[j] + sum_k W_eff[j][k] * coarse_vec(m)[k]
// 8 matches per block; W_effT streamed once per 8 matches. grid=ceil(2M/8)
// ---------------------------------------------------------------------------
__global__ void k_coarse(const float* __restrict__ c1, const float* __restrict__ c2,
                         const int* __restrict__ bidx, const int* __restrict__ ridx,
                         const int* __restrict__ cidx, int M,
                         const float* __restrict__ W_effT, const float* __restrict__ b_eff,
                         float* __restrict__ c_all) {
    const int m0 = blockIdx.x * 8;
    const int j  = threadIdx.x;  // 0..127
    const int twoM = 2 * M;
    __shared__ float v[8 * CC];

    const int nm = (twoM - m0) < 8 ? (twoM - m0) : 8;
    for (int mm = 0; mm < nm; ++mm) {
        int m = m0 + mm;
        const float* src;
        if (m < M) src = c1 + ((size_t)bidx[m] * (HC * HC) + ridx[m]) * CC;
        else       src = c2 + ((size_t)bidx[m - M] * (HC * HC) + cidx[m - M]) * CC;
        v[mm * CC + j]      = src[j];
        v[mm * CC + j + CF] = src[j + CF];
    }
    __syncthreads();

    float acc[8];
    float be = b_eff[j];
    #pragma unroll
    for (int mm = 0; mm < 8; ++mm) acc[mm] = be;

    for (int k = 0; k < CC; ++k) {
        float wv = W_effT[k * CF + j];
        #pragma unroll
        for (int mm = 0; mm < 8; ++mm)
            acc[mm] += wv * v[mm * CC + k];
    }
    for (int mm = 0; mm < nm; ++mm)
        c_all[(size_t)(m0 + mm) * CF + j] = acc[mm];
}

// ---------------------------------------------------------------------------
// K3: MFMA main. One block (4 waves) per match.
//   A = patch [25(+pad7)][128k] bf16 in LDS, XOR-swizzled (ch ^ ((pos&7)<<3))
//       so ds_read_b128 A-frags are bank-conflict-free (row stride 256B).
//   B = Wm1 bf16 [j][k], frags held in registers (wave w owns cols w*32..+31).
//   out[m][p][j] = (A·Wm1^T)[p][j] + c_all[m][j]
// grid = 2M, block = 256
// ---------------------------------------------------------------------------
__global__ __launch_bounds__(256) void k_main(
    const float* __restrict__ f1, const float* __restrict__ f2,
    const int* __restrict__ bidx, const int* __restrict__ ridx,
    const int* __restrict__ cidx, int M,
    const __bf16* __restrict__ Wm1h, const float* __restrict__ c_all,
    float* __restrict__ out) {

    const int m = blockIdx.x;
    const int t = threadIdx.x;
    const int l    = t & 63;   // lane
    const int wv   = t >> 6;   // wave 0..3 (owns output cols wv*32..wv*32+31)
    const int lo16 = l & 15;
    const int hi   = l >> 4;   // 0..3

    __shared__ __bf16 patch[32 * CF];   // rows 25..31 uninitialized (masked on store)

    // --- B fragments (registers): Wm1[j][k], j = wv*32 + nt2*16 + lo16,
    //     k = kt*32 + hi*8 .. +7  -> contiguous 16B in Wm1h, L2-resident
    bf16x8 bfrag[2][4];
    #pragma unroll
    for (int nt2 = 0; nt2 < 2; ++nt2) {
        const int j = wv * 32 + nt2 * 16 + lo16;
        #pragma unroll
        for (int kt = 0; kt < 4; ++kt)
            bfrag[nt2][kt] = *reinterpret_cast<const bf16x8*>(Wm1h + (size_t)j * CF + kt * 32 + hi * 8);
    }

    // --- gather 5x5 window -> LDS (bf16, swizzled) ---
    const float* img; int b, lin;
    if (m < M) { img = f1; b = bidx[m];     lin = ridx[m]; }
    else       { img = f2; b = bidx[m - M]; lin = cidx[m - M]; }
    const int r  = lin / HC, c = lin - r * HC;
    const int y0 = r * STRIDEF - PADW;   // in [-2, 234] -> y0+4 <= 238 < 240: only low bound can clip
    const int x0 = c * STRIDEF - PADW;

    for (int task = t; task < CF * WIN; task += 256) {
        const int ch = task / WIN;
        const int wy = task - ch * WIN;
        const int y  = y0 + wy;
        const bool yok = (y >= 0);
        const float* rowp = img + (((size_t)b * CF + ch) * HF + (yok ? y : 0)) * HF;
        #pragma unroll
        for (int wx = 0; wx < WIN; ++wx) {
            const int x = x0 + wx;
            const float val = (yok && x >= 0) ? rowp[x] : 0.f;
            const int pos = wy * WIN + wx;
            patch[pos * CF + (ch ^ ((pos & 7) << 3))] = (__bf16)val;
        }
    }
    __syncthreads();

    // --- MFMA: 2 M-tiles x 2 N-tiles x 4 K-steps ---
    f32x4 acc[2][2];
    #pragma unroll
    for (int mt = 0; mt < 2; ++mt)
        #pragma unroll
        for (int nt2 = 0; nt2 < 2; ++nt2)
            acc[mt][nt2] = (f32x4){0.f, 0.f, 0.f, 0.f};

    const int swz = (lo16 & 7) << 3;   // same for row lo16 and row 16+lo16
    #pragma unroll
    for (int kt = 0; kt < 4; ++kt) {
        const int koff = (kt * 32 + hi * 8) ^ swz;
        bf16x8 a0 = *reinterpret_cast<const bf16x8*>(&patch[ lo16       * CF + koff]);
        bf16x8 a1 = *reinterpret_cast<const bf16x8*>(&patch[(16 + lo16) * CF + koff]);
        #pragma unroll
        for (int nt2 = 0; nt2 < 2; ++nt2) {
            acc[0][nt2] = __builtin_amdgcn_mfma_f32_16x16x32_bf16(a0, bfrag[nt2][kt], acc[0][nt2], 0, 0, 0);
            acc[1][nt2] = __builtin_amdgcn_mfma_f32_16x16x32_bf16(a1, bfrag[nt2][kt], acc[1][nt2], 0, 0, 0);
        }
    }

    // --- epilogue: add coarse projection, store (mask p<25) ---
    float* ob = out + (size_t)m * (NPOS * CF);
    #pragma unroll
    for (int nt2 = 0; nt2 < 2; ++nt2) {
        const int j  = wv * 32 + nt2 * 16 + lo16;
        const float cv = c_all[(size_t)m * CF + j];
        #pragma unroll
        for (int mt = 0; mt < 2; ++mt) {
            #pragma unroll
            for (int reg = 0; reg < 4; ++reg) {
                const int p = mt * 16 + hi * 4 + reg;   // C/D row = (lane>>4)*4 + reg
                if (p < NPOS)
                    ob[(size_t)p * CF + j] = acc[mt][nt2][reg] + cv;
            }
        }
    }
}

// ---------------------------------------------------------------------------
extern "C" void kernel_launch(void* const* d_in, const int* in_sizes, int n_in,
                              void* d_out, int out_size, void* d_ws, size_t ws_size,
                              hipStream_t stream) {
    const float* c1      = (const float*)d_in[0];
    const float* c2      = (const float*)d_in[1];
    const float* f1      = (const float*)d_in[2];
    const float* f2      = (const float*)d_in[3];
    const int*   bidx    = (const int*)d_in[4];
    const int*   ridx    = (const int*)d_in[5];
    const int*   cidx    = (const int*)d_in[6];
    const float* W_dp    = (const float*)d_in[9];
    const float* b_dp    = (const float*)d_in[10];
    const float* W_merge = (const float*)d_in[11];
    const float* b_merge = (const float*)d_in[12];
    const int M = in_sizes[4];

    char* ws = (char*)d_ws;
    __bf16* Wm1h  = (__bf16*)(ws);                //  32 KB
    float* W_effT = (float*)(ws + (64 << 10));    // 128 KB
    float* b_eff  = (float*)(ws + (192 << 10));   // 512 B
    float* c_all  = (float*)(ws + (256 << 10));   // 2M*128*4 ~ 3.07 MB

    hipLaunchKernelGGL(k_prep, dim3(CC), dim3(CF), 0, stream,
                       W_dp, b_dp, W_merge, b_merge, Wm1h, W_effT, b_eff);
    hipLaunchKernelGGL(k_coarse, dim3((2 * M + 7) / 8), dim3(CF), 0, stream,
                       c1, c2, bidx, ridx, cidx, M, W_effT, b_eff, c_all);
    hipLaunchKernelGGL(k_main, dim3(2 * M), dim3(256), 0, stream,
                       f1, f2, bidx, ridx, cidx, M, Wm1h, c_all, (float*)d_out);
}

// Round 3
// 110.472 us; speedup vs baseline: 2.3400x; 1.7313x over previous
//
#include <hip/hip_runtime.h>

#define HF 240      // fine height/width
#define HC 60       // coarse height/width
#define STRIDEF 4   // HF/HC
#define PADW 2      // WINDOW//2
#define WIN 5
#define CC 256      // C_COARSE
#define CF 128      // C_FINE
#define NPOS 25     // WIN*WIN
#define NPX (HF*HF) // 57600 pixels per image
#define MPB 16      // matches per block in k_coarse

typedef __bf16 bf16x8 __attribute__((ext_vector_type(8)));
typedef __bf16 bf16x4 __attribute__((ext_vector_type(4)));
typedef float  f32x4  __attribute__((ext_vector_type(4)));

// ---------------------------------------------------------------------------
// K1: grid=128 (j), block=256 (k).  All loads coalesced or wave-uniform.
//   Wm1h[j][k<128] = bf16(W_merge[j][k])
//   W_effT[k][j]   = sum_q Wm2[j][q] * W_dp[q][k]
//   b_eff[j]       = Wm2[j]·b_dp + b_merge[j]
// ---------------------------------------------------------------------------
__global__ void k_prep(const float* __restrict__ W_dp, const float* __restrict__ b_dp,
                       const float* __restrict__ W_merge, const float* __restrict__ b_merge,
                       __bf16* __restrict__ Wm1h, float* __restrict__ W_effT,
                       float* __restrict__ b_eff) {
    const int j = blockIdx.x;    // 0..127 output channel
    const int k = threadIdx.x;   // 0..255 coarse dim
    const float* wm2 = W_merge + (size_t)j * (2 * CF) + CF;

    float acc = 0.f, accb = 0.f;
    for (int q = 0; q < CF; ++q) {
        const float wq = wm2[q];                    // wave-uniform -> s_load
        acc  += wq * W_dp[(size_t)q * CC + k];      // coalesced
        accb += wq * b_dp[q];
    }
    W_effT[(size_t)k * CF + j] = acc;

    if (k < CF)
        Wm1h[(size_t)j * CF + k] = (__bf16)W_merge[(size_t)j * (2 * CF) + k];
    if (k == 0)
        b_eff[j] = accb + b_merge[j];
}

// ---------------------------------------------------------------------------
// K2: c_all[m][j] = b_eff[j] + sum_k W_eff[j][k] * coarse_vec(m)[k]
// 16 matches/block; W_effT streamed once per 16 matches. grid=ceil(2M/16)
// ---------------------------------------------------------------------------
__global__ void k_coarse(const float* __restrict__ c1, const float* __restrict__ c2,
                         const int* __restrict__ bidx, const int* __restrict__ ridx,
                         const int* __restrict__ cidx, int M,
                         const float* __restrict__ W_effT, const float* __restrict__ b_eff,
                         float* __restrict__ c_all) {
    const int m0 = blockIdx.x * MPB;
    const int j  = threadIdx.x;  // 0..127
    const int twoM = 2 * M;
    __shared__ float v[MPB * CC];   // 16 KB

    const int nm = (twoM - m0) < MPB ? (twoM - m0) : MPB;
    for (int mm = 0; mm < nm; ++mm) {
        int m = m0 + mm;
        const float* src;
        if (m < M) src = c1 + ((size_t)bidx[m] * (HC * HC) + ridx[m]) * CC;
        else       src = c2 + ((size_t)bidx[m - M] * (HC * HC) + cidx[m - M]) * CC;
        v[mm * CC + j]      = src[j];
        v[mm * CC + j + CF] = src[j + CF];
    }
    __syncthreads();

    float acc[MPB];
    const float be = b_eff[j];
    #pragma unroll
    for (int mm = 0; mm < MPB; ++mm) acc[mm] = be;

    for (int k = 0; k < CC; k += 4) {
        float w0 = W_effT[(k + 0) * CF + j];
        float w1 = W_effT[(k + 1) * CF + j];
        float w2 = W_effT[(k + 2) * CF + j];
        float w3 = W_effT[(k + 3) * CF + j];
        #pragma unroll
        for (int mm = 0; mm < MPB; ++mm) {
            const f32x4 vv = *(const f32x4*)&v[mm * CC + k];
            acc[mm] += w0 * vv.x + w1 * vv.y + w2 * vv.z + w3 * vv.w;
        }
    }
    for (int mm = 0; mm < nm; ++mm)
        c_all[(size_t)(m0 + mm) * CF + j] = acc[mm];
}

// ---------------------------------------------------------------------------
// KT: transpose fine images NCHW fp32 -> T[slot][pixel][ch] bf16.
// slot = img*2 + batch. grid=(900,4), block=256. Tile: 64 px x 128 ch.
// ---------------------------------------------------------------------------
__global__ __launch_bounds__(256) void k_transpose(
    const float* __restrict__ f1, const float* __restrict__ f2,
    __bf16* __restrict__ T) {
    const int slot = blockIdx.y;
    const float* src = (slot >= 2 ? f2 : f1) + (size_t)(slot & 1) * CF * NPX;
    const int px0 = blockIdx.x * 64;
    const int t = threadIdx.x;

    __shared__ __bf16 tile[64 * CF];   // 16 KB, swizzled: ch' = ch ^ ((px&15)<<3)

    // phase 1: column loads (coalesced over px), transpose into LDS
    const int px_l  = t & 63;
    const int chseg = t >> 6;          // 0..3
    const int sw = (px_l & 15) << 3;
    const float* colp = src + px0 + px_l;
    #pragma unroll
    for (int q = 0; q < 8; ++q) {
        const int ch0 = chseg * 32 + q * 4;
        const float v0 = colp[(size_t)(ch0 + 0) * NPX];
        const float v1 = colp[(size_t)(ch0 + 1) * NPX];
        const float v2 = colp[(size_t)(ch0 + 2) * NPX];
        const float v3 = colp[(size_t)(ch0 + 3) * NPX];
        bf16x4 pk = { (__bf16)v0, (__bf16)v1, (__bf16)v2, (__bf16)v3 };
        *(bf16x4*)&tile[px_l * CF + (ch0 ^ sw)] = pk;
    }
    __syncthreads();

    // phase 2: row reads, 1KB-contiguous 16B stores (4 px-rows per instr)
    const int l = t & 63;
    const int w = t >> 6;
    __bf16* dst = T + ((size_t)slot * NPX + px0) * CF;
    #pragma unroll
    for (int i = 0; i < 4; ++i) {
        const int pr  = w * 16 + i * 4 + (l >> 4);
        const int ch0 = (l & 15) * 8;
        const bf16x8 vv = *(const bf16x8*)&tile[pr * CF + (ch0 ^ ((pr & 15) << 3))];
        *(bf16x8*)&dst[(size_t)pr * CF + ch0] = vv;
    }
}

// ---------------------------------------------------------------------------
// K3: MFMA main, gather from pixel-major bf16 T (256B contiguous per pos).
// grid = 2M, block = 256 (4 waves).
// ---------------------------------------------------------------------------
__global__ __launch_bounds__(256) void k_main(
    const __bf16* __restrict__ T,
    const int* __restrict__ bidx, const int* __restrict__ ridx,
    const int* __restrict__ cidx, int M,
    const __bf16* __restrict__ Wm1h, const float* __restrict__ c_all,
    float* __restrict__ out) {

    const int m = blockIdx.x;
    const int t = threadIdx.x;
    const int l    = t & 63;
    const int wv   = t >> 6;
    const int lo16 = l & 15;
    const int hi   = l >> 4;

    __shared__ uint patchU[32 * 64];   // = bf16 patch[32][128], swizzled
    __bf16* patch = (__bf16*)patchU;

    int b, lin, ii;
    if (m < M) { ii = 0; b = bidx[m];     lin = ridx[m]; }
    else       { ii = 1; b = bidx[m - M]; lin = cidx[m - M]; }
    const int slot = ii * 2 + b;
    const int r  = lin / HC, c = lin - r * HC;
    const int y0 = r * STRIDEF - PADW;   // upper bound can't clip (max 238)
    const int x0 = c * STRIDEF - PADW;

    // B fragments from Wm1h (L2-resident)
    bf16x8 bfrag[2][4];
    #pragma unroll
    for (int nt2 = 0; nt2 < 2; ++nt2) {
        const int j = wv * 32 + nt2 * 16 + lo16;
        #pragma unroll
        for (int kt = 0; kt < 4; ++kt)
            bfrag[nt2][kt] = *reinterpret_cast<const bf16x8*>(Wm1h + (size_t)j * CF + kt * 32 + hi * 8);
    }

    // gather: wave wv handles positions p = wv, wv+4, ...; 256B coalesced each
    const uint* Tb32 = (const uint*)(T + (size_t)slot * NPX * CF);
    for (int p = wv; p < NPOS; p += 4) {
        const int wy = p / WIN, wx = p - wy * WIN;
        const int y = y0 + wy, x = x0 + wx;
        uint v = 0;
        if (y >= 0 && x >= 0)
            v = Tb32[(size_t)(y * HF + x) * (CF / 2) + l];
        patchU[p * 64 + (l ^ ((p & 7) << 2))] = v;   // == patch[p][2l ^ ((p&7)<<3)]
    }
    __syncthreads();

    // MFMA: 2 M-tiles x 2 N-tiles x 4 K-steps
    f32x4 acc[2][2];
    #pragma unroll
    for (int mt = 0; mt < 2; ++mt)
        #pragma unroll
        for (int nt2 = 0; nt2 < 2; ++nt2)
            acc[mt][nt2] = (f32x4){0.f, 0.f, 0.f, 0.f};

    const int swz = (lo16 & 7) << 3;
    #pragma unroll
    for (int kt = 0; kt < 4; ++kt) {
        const int koff = (kt * 32 + hi * 8) ^ swz;
        bf16x8 a0 = *reinterpret_cast<const bf16x8*>(&patch[ lo16       * CF + koff]);
        bf16x8 a1 = *reinterpret_cast<const bf16x8*>(&patch[(16 + lo16) * CF + koff]);
        #pragma unroll
        for (int nt2 = 0; nt2 < 2; ++nt2) {
            acc[0][nt2] = __builtin_amdgcn_mfma_f32_16x16x32_bf16(a0, bfrag[nt2][kt], acc[0][nt2], 0, 0, 0);
            acc[1][nt2] = __builtin_amdgcn_mfma_f32_16x16x32_bf16(a1, bfrag[nt2][kt], acc[1][nt2], 0, 0, 0);
        }
    }

    // epilogue
    float* ob = out + (size_t)m * (NPOS * CF);
    #pragma unroll
    for (int nt2 = 0; nt2 < 2; ++nt2) {
        const int j  = wv * 32 + nt2 * 16 + lo16;
        const float cv = c_all[(size_t)m * CF + j];
        #pragma unroll
        for (int mt = 0; mt < 2; ++mt) {
            #pragma unroll
            for (int reg = 0; reg < 4; ++reg) {
                const int p = mt * 16 + hi * 4 + reg;
                if (p < NPOS)
                    ob[(size_t)p * CF + j] = acc[mt][nt2][reg] + cv;
            }
        }
    }
}

// ---------------------------------------------------------------------------
// Fallback main (R2 path): gather directly from fp32 NCHW images.
// ---------------------------------------------------------------------------
__global__ __launch_bounds__(256) void k_main_direct(
    const float* __restrict__ f1, const float* __restrict__ f2,
    const int* __restrict__ bidx, const int* __restrict__ ridx,
    const int* __restrict__ cidx, int M,
    const __bf16* __restrict__ Wm1h, const float* __restrict__ c_all,
    float* __restrict__ out) {

    const int m = blockIdx.x;
    const int t = threadIdx.x;
    const int l    = t & 63;
    const int wv   = t >> 6;
    const int lo16 = l & 15;
    const int hi   = l >> 4;

    __shared__ __bf16 patch[32 * CF];

    bf16x8 bfrag[2][4];
    #pragma unroll
    for (int nt2 = 0; nt2 < 2; ++nt2) {
        const int j = wv * 32 + nt2 * 16 + lo16;
        #pragma unroll
        for (int kt = 0; kt < 4; ++kt)
            bfrag[nt2][kt] = *reinterpret_cast<const bf16x8*>(Wm1h + (size_t)j * CF + kt * 32 + hi * 8);
    }

    const float* img; int b, lin;
    if (m < M) { img = f1; b = bidx[m];     lin = ridx[m]; }
    else       { img = f2; b = bidx[m - M]; lin = cidx[m - M]; }
    const int r  = lin / HC, c = lin - r * HC;
    const int y0 = r * STRIDEF - PADW;
    const int x0 = c * STRIDEF - PADW;

    for (int task = t; task < CF * WIN; task += 256) {
        const int ch = task / WIN;
        const int wy = task - ch * WIN;
        const int y  = y0 + wy;
        const bool yok = (y >= 0);
        const float* rowp = img + (((size_t)b * CF + ch) * HF + (yok ? y : 0)) * HF;
        #pragma unroll
        for (int wx = 0; wx < WIN; ++wx) {
            const int x = x0 + wx;
            const float val = (yok && x >= 0) ? rowp[x] : 0.f;
            const int pos = wy * WIN + wx;
            patch[pos * CF + (ch ^ ((pos & 7) << 3))] = (__bf16)val;
        }
    }
    __syncthreads();

    f32x4 acc[2][2];
    #pragma unroll
    for (int mt = 0; mt < 2; ++mt)
        #pragma unroll
        for (int nt2 = 0; nt2 < 2; ++nt2)
            acc[mt][nt2] = (f32x4){0.f, 0.f, 0.f, 0.f};

    const int swz = (lo16 & 7) << 3;
    #pragma unroll
    for (int kt = 0; kt < 4; ++kt) {
        const int koff = (kt * 32 + hi * 8) ^ swz;
        bf16x8 a0 = *reinterpret_cast<const bf16x8*>(&patch[ lo16       * CF + koff]);
        bf16x8 a1 = *reinterpret_cast<const bf16x8*>(&patch[(16 + lo16) * CF + koff]);
        #pragma unroll
        for (int nt2 = 0; nt2 < 2; ++nt2) {
            acc[0][nt2] = __builtin_amdgcn_mfma_f32_16x16x32_bf16(a0, bfrag[nt2][kt], acc[0][nt2], 0, 0, 0);
            acc[1][nt2] = __builtin_amdgcn_mfma_f32_16x16x32_bf16(a1, bfrag[nt2][kt], acc[1][nt2], 0, 0, 0);
        }
    }

    float* ob = out + (size_t)m * (NPOS * CF);
    #pragma unroll
    for (int nt2 = 0; nt2 < 2; ++nt2) {
        const int j  = wv * 32 + nt2 * 16 + lo16;
        const float cv = c_all[(size_t)m * CF + j];
        #pragma unroll
        for (int mt = 0; mt < 2; ++mt) {
            #pragma unroll
            for (int reg = 0; reg < 4; ++reg) {
                const int p = mt * 16 + hi * 4 + reg;
                if (p < NPOS)
                    ob[(size_t)p * CF + j] = acc[mt][nt2][reg] + cv;
            }
        }
    }
}

// ---------------------------------------------------------------------------
extern "C" void kernel_launch(void* const* d_in, const int* in_sizes, int n_in,
                              void* d_out, int out_size, void* d_ws, size_t ws_size,
                              hipStream_t stream) {
    const float* c1      = (const float*)d_in[0];
    const float* c2      = (const float*)d_in[1];
    const float* f1      = (const float*)d_in[2];
    const float* f2      = (const float*)d_in[3];
    const int*   bidx    = (const int*)d_in[4];
    const int*   ridx    = (const int*)d_in[5];
    const int*   cidx    = (const int*)d_in[6];
    const float* W_dp    = (const float*)d_in[9];
    const float* b_dp    = (const float*)d_in[10];
    const float* W_merge = (const float*)d_in[11];
    const float* b_merge = (const float*)d_in[12];
    const int M = in_sizes[4];

    char* ws = (char*)d_ws;
    __bf16* Wm1h  = (__bf16*)(ws);                //  32 KB
    float* W_effT = (float*)(ws + (64 << 10));    // 128 KB
    float* b_eff  = (float*)(ws + (192 << 10));   // 512 B
    float* c_all  = (float*)(ws + (256 << 10));   // 2M*128*4 ~ 3.07 MB
    __bf16* T     = (__bf16*)(ws + (4 << 20));    // 4*57600*128*2 = 58.98 MB

    const size_t need_T = (size_t)(4 << 20) + (size_t)4 * NPX * CF * 2;

    hipLaunchKernelGGL(k_prep, dim3(CF), dim3(CC), 0, stream,
                       W_dp, b_dp, W_merge, b_merge, Wm1h, W_effT, b_eff);

    if (ws_size >= need_T) {
        hipLaunchKernelGGL(k_transpose, dim3(NPX / 64, 4), dim3(256), 0, stream,
                           f1, f2, T);
        hipLaunchKernelGGL(k_coarse, dim3((2 * M + MPB - 1) / MPB), dim3(CF), 0, stream,
                           c1, c2, bidx, ridx, cidx, M, W_effT, b_eff, c_all);
        hipLaunchKernelGGL(k_main, dim3(2 * M), dim3(256), 0, stream,
                           T, bidx, ridx, cidx, M, Wm1h, c_all, (float*)d_out);
    } else {
        hipLaunchKernelGGL(k_coarse, dim3((2 * M + MPB - 1) / MPB), dim3(CF), 0, stream,
                           c1, c2, bidx, ridx, cidx, M, W_effT, b_eff, c_all);
        hipLaunchKernelGGL(k_main_direct, dim3(2 * M), dim3(256), 0, stream,
                           f1, f2, bidx, ridx, cidx, M, Wm1h, c_all, (float*)d_out);
    }
}

// Round 4
// 99.450 us; speedup vs baseline: 2.5993x; 1.1108x over previous
//
#include <hip/hip_runtime.h>

#define HF 240      // fine height/width
#define HC 60       // coarse height/width
#define STRIDEF 4   // HF/HC
#define PADW 2      // WINDOW//2
#define WIN 5
#define CC 256      // C_COARSE
#define CF 128      // C_FINE
#define NPOS 25     // WIN*WIN
#define NPX (HF*HF) // 57600 pixels per image
#define MPB 16      // matches per block in k_coarse
#define PXT 64      // px per k_tgemm tile

typedef __bf16 bf16x8 __attribute__((ext_vector_type(8)));
typedef __bf16 bf16x4 __attribute__((ext_vector_type(4)));
typedef float  f32x4  __attribute__((ext_vector_type(4)));

// ---------------------------------------------------------------------------
// K1: grid=128 (j), block=256 (k).
//   Wm1h[j][k<128] = bf16(W_merge[j][k])
//   W_effT[k][j]   = sum_q Wm2[j][q] * W_dp[q][k]
//   b_eff[j]       = Wm2[j]·b_dp + b_merge[j]
// ---------------------------------------------------------------------------
__global__ void k_prep(const float* __restrict__ W_dp, const float* __restrict__ b_dp,
                       const float* __restrict__ W_merge, const float* __restrict__ b_merge,
                       __bf16* __restrict__ Wm1h, float* __restrict__ W_effT,
                       float* __restrict__ b_eff) {
    const int j = blockIdx.x;    // 0..127 output channel
    const int k = threadIdx.x;   // 0..255 coarse dim
    const float* wm2 = W_merge + (size_t)j * (2 * CF) + CF;

    float acc = 0.f, accb = 0.f;
    for (int q = 0; q < CF; ++q) {
        const float wq = wm2[q];                    // wave-uniform
        acc  += wq * W_dp[(size_t)q * CC + k];      // coalesced
        accb += wq * b_dp[q];
    }
    W_effT[(size_t)k * CF + j] = acc;

    if (k < CF)
        Wm1h[(size_t)j * CF + k] = (__bf16)W_merge[(size_t)j * (2 * CF) + k];
    if (k == 0)
        b_eff[j] = accb + b_merge[j];
}

// ---------------------------------------------------------------------------
// K2: c_all[m][j] = b_eff[j] + sum_k W_eff[j][k] * coarse_vec(m)[k]
// ---------------------------------------------------------------------------
__global__ void k_coarse(const float* __restrict__ c1, const float* __restrict__ c2,
                         const int* __restrict__ bidx, const int* __restrict__ ridx,
                         const int* __restrict__ cidx, int M,
                         const float* __restrict__ W_effT, const float* __restrict__ b_eff,
                         float* __restrict__ c_all) {
    const int m0 = blockIdx.x * MPB;
    const int j  = threadIdx.x;  // 0..127
    const int twoM = 2 * M;
    __shared__ float v[MPB * CC];   // 16 KB

    const int nm = (twoM - m0) < MPB ? (twoM - m0) : MPB;
    for (int mm = 0; mm < nm; ++mm) {
        int m = m0 + mm;
        const float* src;
        if (m < M) src = c1 + ((size_t)bidx[m] * (HC * HC) + ridx[m]) * CC;
        else       src = c2 + ((size_t)bidx[m - M] * (HC * HC) + cidx[m - M]) * CC;
        v[mm * CC + j]      = src[j];
        v[mm * CC + j + CF] = src[j + CF];
    }
    __syncthreads();

    float acc[MPB];
    const float be = b_eff[j];
    #pragma unroll
    for (int mm = 0; mm < MPB; ++mm) acc[mm] = be;

    for (int k = 0; k < CC; k += 4) {
        float w0 = W_effT[(k + 0) * CF + j];
        float w1 = W_effT[(k + 1) * CF + j];
        float w2 = W_effT[(k + 2) * CF + j];
        float w3 = W_effT[(k + 3) * CF + j];
        #pragma unroll
        for (int mm = 0; mm < MPB; ++mm) {
            const f32x4 vv = *(const f32x4*)&v[mm * CC + k];
            acc[mm] += w0 * vv.x + w1 * vv.y + w2 * vv.z + w3 * vv.w;
        }
    }
    for (int mm = 0; mm < nm; ++mm)
        c_all[(size_t)(m0 + mm) * CF + j] = acc[mm];
}

// ---------------------------------------------------------------------------
// KTG: fused transpose + GEMM. Per block: 64px x 128ch fp32 tile of one
// image slot -> bf16 LDS (swizzled) -> V[px][j] = patch · Wm1^T (bf16 out).
//   loads:  float4 along px (16B/lane), 8 per thread
//   LDS:    patch[px][ch ^ ((px>>2)<<3)]  (b128-read-compatible swizzle)
//   MFMA:   4 M-tiles x 2 N-tiles x 4 K-steps per wave (wave owns 32 j)
// grid=(900,4), block=256.
// ---------------------------------------------------------------------------
__global__ __launch_bounds__(256) void k_tgemm(
    const float* __restrict__ f1, const float* __restrict__ f2,
    const __bf16* __restrict__ Wm1h, __bf16* __restrict__ V) {

    const int slot = blockIdx.y;
    const float* src = (slot >= 2 ? f2 : f1) + (size_t)(slot & 1) * CF * NPX;
    const int px0 = blockIdx.x * PXT;
    const int t  = threadIdx.x;
    const int l  = t & 63;
    const int w  = t >> 6;
    const int lo16 = l & 15;
    const int hi   = l >> 4;

    __shared__ __bf16 patch[PXT * CF];   // 16 KB

    // B fragments: Wm1[j][k], j = w*32 + nt2*16 + lo16 (L2-resident)
    bf16x8 bfrag[2][4];
    #pragma unroll
    for (int nt2 = 0; nt2 < 2; ++nt2) {
        const int j = w * 32 + nt2 * 16 + lo16;
        #pragma unroll
        for (int kt = 0; kt < 4; ++kt)
            bfrag[nt2][kt] = *reinterpret_cast<const bf16x8*>(Wm1h + (size_t)j * CF + kt * 32 + hi * 8);
    }

    // phase 1: float4 loads along px, cvt, swizzled bf16 LDS writes
    // lane: px = 4*(l&15)+i, ch = w*32 + q*4 + (l>>4)
    const int pxl = 4 * lo16;
    const int sw  = lo16 << 3;          // (px>>2)<<3, px>>2 == lo16
    #pragma unroll
    for (int q = 0; q < 8; ++q) {
        const int ch = w * 32 + q * 4 + hi;
        const f32x4 vv = *reinterpret_cast<const f32x4*>(src + (size_t)ch * NPX + px0 + pxl);
        const int chs = ch ^ sw;
        patch[(pxl + 0) * CF + chs] = (__bf16)vv.x;
        patch[(pxl + 1) * CF + chs] = (__bf16)vv.y;
        patch[(pxl + 2) * CF + chs] = (__bf16)vv.z;
        patch[(pxl + 3) * CF + chs] = (__bf16)vv.w;
    }
    __syncthreads();

    // phase 2: MFMA
    f32x4 acc[4][2];
    #pragma unroll
    for (int mt = 0; mt < 4; ++mt)
        #pragma unroll
        for (int nt2 = 0; nt2 < 2; ++nt2)
            acc[mt][nt2] = (f32x4){0.f, 0.f, 0.f, 0.f};

    #pragma unroll
    for (int kt = 0; kt < 4; ++kt) {
        const int k0 = kt * 32 + hi * 8;
        #pragma unroll
        for (int mt = 0; mt < 4; ++mt) {
            const int px = mt * 16 + lo16;
            const int koff = k0 ^ ((px >> 2) << 3);
            bf16x8 a = *reinterpret_cast<const bf16x8*>(&patch[px * CF + koff]);
            #pragma unroll
            for (int nt2 = 0; nt2 < 2; ++nt2)
                acc[mt][nt2] = __builtin_amdgcn_mfma_f32_16x16x32_bf16(a, bfrag[nt2][kt], acc[mt][nt2], 0, 0, 0);
        }
    }

    // epilogue: V[slot][px][j] = bf16(acc)
    __bf16* Vp = V + ((size_t)slot * NPX + px0) * CF;
    #pragma unroll
    for (int mt = 0; mt < 4; ++mt) {
        #pragma unroll
        for (int nt2 = 0; nt2 < 2; ++nt2) {
            const int j = w * 32 + nt2 * 16 + lo16;
            #pragma unroll
            for (int reg = 0; reg < 4; ++reg) {
                const int px = mt * 16 + hi * 4 + reg;
                Vp[(size_t)px * CF + j] = (__bf16)acc[mt][nt2][reg];
            }
        }
    }
}

// ---------------------------------------------------------------------------
// K4: pure gather-add stream: out[m][p][j] = V[slot][y,x][j] + c_all[m][j]
// grid = 2M, block = 256. No LDS, no sync.
// ---------------------------------------------------------------------------
__global__ __launch_bounds__(256) void k_gather(
    const __bf16* __restrict__ V,
    const int* __restrict__ bidx, const int* __restrict__ ridx,
    const int* __restrict__ cidx, int M,
    const float* __restrict__ c_all, float* __restrict__ out) {

    const int m = blockIdx.x;
    const int t = threadIdx.x;
    const int g  = t >> 5;    // row group 0..7
    const int l32 = t & 31;   // covers 128 ch as 32 float4

    int b, lin, ii;
    if (m < M) { ii = 0; b = bidx[m];     lin = ridx[m]; }
    else       { ii = 1; b = bidx[m - M]; lin = cidx[m - M]; }
    const int slot = ii * 2 + b;
    const int r  = lin / HC, c = lin - r * HC;
    const int y0 = r * STRIDEF - PADW;
    const int x0 = c * STRIDEF - PADW;

    const f32x4 c4 = *reinterpret_cast<const f32x4*>(c_all + (size_t)m * CF + l32 * 4);
    const __bf16* Vb = V + (size_t)slot * NPX * CF;
    float* ob = out + (size_t)m * (NPOS * CF) + l32 * 4;

    #pragma unroll
    for (int pass = 0; pass < 4; ++pass) {
        const int p = pass * 8 + g;
        if (p < NPOS) {
            const int wy = (p * 13) >> 6;      // p/5 for p<32
            const int wx = p - wy * WIN;
            const int y = y0 + wy, x = x0 + wx;
            f32x4 o = c4;
            if (y >= 0 && x >= 0) {
                const bf16x4 v = *reinterpret_cast<const bf16x4*>(Vb + (size_t)(y * HF + x) * CF + l32 * 4);
                o.x += (float)v.x; o.y += (float)v.y; o.z += (float)v.z; o.w += (float)v.w;
            }
            *reinterpret_cast<f32x4*>(ob + (size_t)p * CF) = o;
        }
    }
}

// ---------------------------------------------------------------------------
// Fallback main (R2 path): gather directly from fp32 NCHW images.
// ---------------------------------------------------------------------------
__global__ __launch_bounds__(256) void k_main_direct(
    const float* __restrict__ f1, const float* __restrict__ f2,
    const int* __restrict__ bidx, const int* __restrict__ ridx,
    const int* __restrict__ cidx, int M,
    const __bf16* __restrict__ Wm1h, const float* __restrict__ c_all,
    float* __restrict__ out) {

    const int m = blockIdx.x;
    const int t = threadIdx.x;
    const int l    = t & 63;
    const int wv   = t >> 6;
    const int lo16 = l & 15;
    const int hi   = l >> 4;

    __shared__ __bf16 patch[32 * CF];

    bf16x8 bfrag[2][4];
    #pragma unroll
    for (int nt2 = 0; nt2 < 2; ++nt2) {
        const int j = wv * 32 + nt2 * 16 + lo16;
        #pragma unroll
        for (int kt = 0; kt < 4; ++kt)
            bfrag[nt2][kt] = *reinterpret_cast<const bf16x8*>(Wm1h + (size_t)j * CF + kt * 32 + hi * 8);
    }

    const float* img; int b, lin;
    if (m < M) { img = f1; b = bidx[m];     lin = ridx[m]; }
    else       { img = f2; b = bidx[m - M]; lin = cidx[m - M]; }
    const int r  = lin / HC, c = lin - r * HC;
    const int y0 = r * STRIDEF - PADW;
    const int x0 = c * STRIDEF - PADW;

    for (int task = t; task < CF * WIN; task += 256) {
        const int ch = task / WIN;
        const int wy = task - ch * WIN;
        const int y  = y0 + wy;
        const bool yok = (y >= 0);
        const float* rowp = img + (((size_t)b * CF + ch) * HF + (yok ? y : 0)) * HF;
        #pragma unroll
        for (int wx = 0; wx < WIN; ++wx) {
            const int x = x0 + wx;
            const float val = (yok && x >= 0) ? rowp[x] : 0.f;
            const int pos = wy * WIN + wx;
            patch[pos * CF + (ch ^ ((pos & 7) << 3))] = (__bf16)val;
        }
    }
    __syncthreads();

    f32x4 acc[2][2];
    #pragma unroll
    for (int mt = 0; mt < 2; ++mt)
        #pragma unroll
        for (int nt2 = 0; nt2 < 2; ++nt2)
            acc[mt][nt2] = (f32x4){0.f, 0.f, 0.f, 0.f};

    const int swz = (lo16 & 7) << 3;
    #pragma unroll
    for (int kt = 0; kt < 4; ++kt) {
        const int koff = (kt * 32 + hi * 8) ^ swz;
        bf16x8 a0 = *reinterpret_cast<const bf16x8*>(&patch[ lo16       * CF + koff]);
        bf16x8 a1 = *reinterpret_cast<const bf16x8*>(&patch[(16 + lo16) * CF + koff]);
        #pragma unroll
        for (int nt2 = 0; nt2 < 2; ++nt2) {
            acc[0][nt2] = __builtin_amdgcn_mfma_f32_16x16x32_bf16(a0, bfrag[nt2][kt], acc[0][nt2], 0, 0, 0);
            acc[1][nt2] = __builtin_amdgcn_mfma_f32_16x16x32_bf16(a1, bfrag[nt2][kt], acc[1][nt2], 0, 0, 0);
        }
    }

    float* ob = out + (size_t)m * (NPOS * CF);
    #pragma unroll
    for (int nt2 = 0; nt2 < 2; ++nt2) {
        const int j  = wv * 32 + nt2 * 16 + lo16;
        const float cv = c_all[(size_t)m * CF + j];
        #pragma unroll
        for (int mt = 0; mt < 2; ++mt) {
            #pragma unroll
            for (int reg = 0; reg < 4; ++reg) {
                const int p = mt * 16 + hi * 4 + reg;
                if (p < NPOS)
                    ob[(size_t)p * CF + j] = acc[mt][nt2][reg] + cv;
            }
        }
    }
}

// ---------------------------------------------------------------------------
extern "C" void kernel_launch(void* const* d_in, const int* in_sizes, int n_in,
                              void* d_out, int out_size, void* d_ws, size_t ws_size,
                              hipStream_t stream) {
    const float* c1      = (const float*)d_in[0];
    const float* c2      = (const float*)d_in[1];
    const float* f1      = (const float*)d_in[2];
    const float* f2      = (const float*)d_in[3];
    const int*   bidx    = (const int*)d_in[4];
    const int*   ridx    = (const int*)d_in[5];
    const int*   cidx    = (const int*)d_in[6];
    const float* W_dp    = (const float*)d_in[9];
    const float* b_dp    = (const float*)d_in[10];
    const float* W_merge = (const float*)d_in[11];
    const float* b_merge = (const float*)d_in[12];
    const int M = in_sizes[4];

    char* ws = (char*)d_ws;
    __bf16* Wm1h  = (__bf16*)(ws);                //  32 KB
    float* W_effT = (float*)(ws + (64 << 10));    // 128 KB
    float* b_eff  = (float*)(ws + (192 << 10));   // 512 B
    float* c_all  = (float*)(ws + (256 << 10));   // 2M*128*4 ~ 3.07 MB
    __bf16* V     = (__bf16*)(ws + (4 << 20));    // 4*57600*128*2 = 58.98 MB

    const size_t need_V = (size_t)(4 << 20) + (size_t)4 * NPX * CF * 2;

    hipLaunchKernelGGL(k_prep, dim3(CF), dim3(CC), 0, stream,
                       W_dp, b_dp, W_merge, b_merge, Wm1h, W_effT, b_eff);
    hipLaunchKernelGGL(k_coarse, dim3((2 * M + MPB - 1) / MPB), dim3(CF), 0, stream,
                       c1, c2, bidx, ridx, cidx, M, W_effT, b_eff, c_all);

    if (ws_size >= need_V) {
        hipLaunchKernelGGL(k_tgemm, dim3(NPX / PXT, 4), dim3(256), 0, stream,
                           f1, f2, Wm1h, V);
        hipLaunchKernelGGL(k_gather, dim3(2 * M), dim3(256), 0, stream,
                           V, bidx, ridx, cidx, M, c_all, (float*)d_out);
    } else {
        hipLaunchKernelGGL(k_main_direct, dim3(2 * M), dim3(256), 0, stream,
                           f1, f2, bidx, ridx, cidx, M, Wm1h, c_all, (float*)d_out);
    }
}